// Round 1
// baseline (1461.506 us; speedup 1.0000x reference)
//
#include <hip/hip_runtime.h>
#include <hip/hip_bf16.h>

#define NN 50000
#define EE 800000
#define DD 64

// ---------------- degree histogram (fp32 counts are exact up to 2^24) ----
__global__ void deg_kernel(const int* __restrict__ dst, float* __restrict__ deg) {
    int e = blockIdx.x * 256 + threadIdx.x;
    if (e < EE) atomicAdd(&deg[dst[e]], 1.0f);
}

// ---------------- inv_deg in place: deg>0 ? 1/deg : 0 ---------------------
__global__ void inv_kernel(float* __restrict__ deg) {
    int i = blockIdx.x * 256 + threadIdx.x;
    if (i < NN) {
        float d = deg[i];
        deg[i] = (d > 0.0f) ? (1.0f / d) : 0.0f;
    }
}

// ---------------- scatter-add: agg[dst] += feat[src] ----------------------
// 16 threads per edge, each handles one float4 (coalesced 256B row reads).
__global__ void scatter_kernel(const float* __restrict__ feat,
                               const int* __restrict__ src,
                               const int* __restrict__ dst,
                               float* __restrict__ agg) {
    unsigned t = blockIdx.x * 256u + threadIdx.x;
    unsigned e = t >> 4;
    if (e >= EE) return;
    unsigned q = (t & 15u) << 2;      // feature offset 0,4,...,60
    int s = src[e];
    int d = dst[e];
    const float4 v = *reinterpret_cast<const float4*>(feat + (size_t)s * DD + q);
    float* p = agg + (size_t)d * DD + q;
    atomicAdd(p + 0, v.x);
    atomicAdd(p + 1, v.y);
    atomicAdd(p + 2, v.z);
    atomicAdd(p + 3, v.w);
}

// ---------------- fused SAGE layer: out = [agg*inv | xin] @ [Wl;Wr] + b ----
// 64 nodes x 64 cols per block. A staged in LDS with XOR swizzle (stride 128),
// W = [Wl;Wr] (128x64) in LDS. Each thread: 4 nodes x 4 cols register tile.
__launch_bounds__(256)
__global__ void layer_kernel(const float* __restrict__ agg,
                             const float* __restrict__ xin,
                             const float* __restrict__ inv,
                             const float* __restrict__ Wl,
                             const float* __restrict__ Wr,
                             const float* __restrict__ bias,
                             float* __restrict__ outp,
                             int relu) {
    __shared__ float A[64 * 128];   // [node][k^sw], sw = (node&7)<<2
    __shared__ float W[128 * 64];   // [k][j]
    const int tid = threadIdx.x;
    const int base = blockIdx.x * 64;

    // stage W = [Wl; Wr]: 8192 floats, 32 per thread as float4 (contiguous)
    #pragma unroll
    for (int i = 0; i < 8; ++i) {
        int idx = (i * 256 + tid) * 4;       // 0..8191
        int k = idx >> 6, j = idx & 63;
        const float* sp = (k < 64) ? (Wl + k * 64 + j) : (Wr + (k - 64) * 64 + j);
        *reinterpret_cast<float4*>(&W[idx]) = *reinterpret_cast<const float4*>(sp);
    }

    // stage A = [agg*inv | xin] for 64 nodes, XOR-swizzled
    #pragma unroll
    for (int i = 0; i < 8; ++i) {
        int t2 = i * 256 + tid;              // 0..2047
        int n  = t2 >> 5;                    // node in tile 0..63
        int c4 = (t2 & 31) * 4;              // k chunk 0,4,...,124
        int node = base + n;
        float4 v = make_float4(0.f, 0.f, 0.f, 0.f);
        if (node < NN) {
            if (c4 < 64) {
                v = *reinterpret_cast<const float4*>(agg + (size_t)node * DD + c4);
                float s = inv[node];
                v.x *= s; v.y *= s; v.z *= s; v.w *= s;
            } else {
                v = *reinterpret_cast<const float4*>(xin + (size_t)node * DD + (c4 - 64));
            }
        }
        int sw = (n & 7) << 2;
        *reinterpret_cast<float4*>(&A[n * 128 + (c4 ^ sw)]) = v;
    }
    __syncthreads();

    const int tc = (tid & 15) * 4;    // col base 0..60
    const int tr = (tid >> 4) * 4;    // node base in tile 0..60

    float acc[4][4];
    float4 bv = *reinterpret_cast<const float4*>(bias + tc);
    #pragma unroll
    for (int i = 0; i < 4; ++i) {
        acc[i][0] = bv.x; acc[i][1] = bv.y; acc[i][2] = bv.z; acc[i][3] = bv.w;
    }

    #pragma unroll 8
    for (int k = 0; k < 128; k += 4) {
        float av[4][4];
        #pragma unroll
        for (int i = 0; i < 4; ++i) {
            int row = tr + i;
            float4 a = *reinterpret_cast<const float4*>(
                &A[row * 128 + (k ^ ((row & 7) << 2))]);
            av[i][0] = a.x; av[i][1] = a.y; av[i][2] = a.z; av[i][3] = a.w;
        }
        #pragma unroll
        for (int kk = 0; kk < 4; ++kk) {
            float4 w = *reinterpret_cast<const float4*>(&W[(k + kk) * 64 + tc]);
            #pragma unroll
            for (int i = 0; i < 4; ++i) {
                acc[i][0] += av[i][kk] * w.x;
                acc[i][1] += av[i][kk] * w.y;
                acc[i][2] += av[i][kk] * w.z;
                acc[i][3] += av[i][kk] * w.w;
            }
        }
    }

    #pragma unroll
    for (int i = 0; i < 4; ++i) {
        int node = base + tr + i;
        if (node < NN) {
            float4 r = make_float4(acc[i][0], acc[i][1], acc[i][2], acc[i][3]);
            if (relu) {
                r.x = fmaxf(r.x, 0.f); r.y = fmaxf(r.y, 0.f);
                r.z = fmaxf(r.z, 0.f); r.w = fmaxf(r.w, 0.f);
            }
            *reinterpret_cast<float4*>(outp + (size_t)node * DD + tc) = r;
        }
    }
}

extern "C" void kernel_launch(void* const* d_in, const int* in_sizes, int n_in,
                              void* d_out, int out_size, void* d_ws, size_t ws_size,
                              hipStream_t stream) {
    const float* x   = (const float*)d_in[0];
    const int*   ei  = (const int*)d_in[1];
    const float* Wl1 = (const float*)d_in[2];
    const float* Wr1 = (const float*)d_in[3];
    const float* b1  = (const float*)d_in[4];
    const float* Wl2 = (const float*)d_in[5];
    const float* Wr2 = (const float*)d_in[6];
    const float* b2  = (const float*)d_in[7];
    float* out = (float*)d_out;

    const int* src = ei;        // edge_index[0]
    const int* dst = ei + EE;   // edge_index[1]

    float* ws  = (float*)d_ws;
    float* deg = ws;                            // N floats (becomes inv_deg)
    float* agg = ws + NN;                       // N*D floats
    float* h   = ws + NN + (size_t)NN * DD;     // N*D floats

    // zero deg + agg in one contiguous memset
    hipMemsetAsync(deg, 0, (size_t)(NN + (size_t)NN * DD) * sizeof(float), stream);

    deg_kernel<<<(EE + 255) / 256, 256, 0, stream>>>(dst, deg);
    inv_kernel<<<(NN + 255) / 256, 256, 0, stream>>>(deg);

    // layer 1
    scatter_kernel<<<(EE * 16 + 255) / 256, 256, 0, stream>>>(x, src, dst, agg);
    layer_kernel<<<(NN + 63) / 64, 256, 0, stream>>>(agg, x, deg, Wl1, Wr1, b1, h, 1);

    // layer 2 (reuse agg buffer)
    hipMemsetAsync(agg, 0, (size_t)NN * DD * sizeof(float), stream);
    scatter_kernel<<<(EE * 16 + 255) / 256, 256, 0, stream>>>(h, src, dst, agg);
    layer_kernel<<<(NN + 63) / 64, 256, 0, stream>>>(agg, h, deg, Wl2, Wr2, b2, out, 0);
}

// Round 2
// 239.812 us; speedup vs baseline: 6.0944x; 6.0944x over previous
//
#include <hip/hip_runtime.h>
#include <hip/hip_bf16.h>

#define NN 50000
#define EE 800000
#define DD 64

// ---------------- degree histogram (int atomics) --------------------------
__global__ void deg_kernel(const int* __restrict__ dst, int* __restrict__ deg) {
    int e = blockIdx.x * 256 + threadIdx.x;
    if (e < EE) atomicAdd(&deg[dst[e]], 1);
}

// ---------------- inv_deg: deg>0 ? 1/deg : 0 -------------------------------
__global__ void inv_kernel(const int* __restrict__ deg, float* __restrict__ inv) {
    int i = blockIdx.x * 256 + threadIdx.x;
    if (i < NN) {
        int d = deg[i];
        inv[i] = (d > 0) ? (1.0f / (float)d) : 0.0f;
    }
}

// ---------------- 3-kernel exclusive scan over deg -> offs ----------------
__global__ void scan1_kernel(const int* __restrict__ deg, int* __restrict__ offs,
                             int* __restrict__ bsum) {
    __shared__ int s[256];
    const int tid = threadIdx.x;
    int i = blockIdx.x * 256 + tid;
    int v = (i < NN) ? deg[i] : 0;
    s[tid] = v;
    __syncthreads();
    #pragma unroll
    for (int o = 1; o < 256; o <<= 1) {
        int t = (tid >= o) ? s[tid - o] : 0;
        __syncthreads();
        s[tid] += t;
        __syncthreads();
    }
    if (i < NN) offs[i] = s[tid] - v;          // exclusive within block
    if (tid == 255) bsum[blockIdx.x] = s[255]; // block total
}

__global__ void scan2_kernel(int* __restrict__ bsum, int nb) {
    __shared__ int s[256];
    const int tid = threadIdx.x;
    int v = (tid < nb) ? bsum[tid] : 0;
    s[tid] = v;
    __syncthreads();
    #pragma unroll
    for (int o = 1; o < 256; o <<= 1) {
        int t = (tid >= o) ? s[tid - o] : 0;
        __syncthreads();
        s[tid] += t;
        __syncthreads();
    }
    if (tid < nb) bsum[tid] = s[tid] - v;      // exclusive
}

__global__ void scan3_kernel(int* __restrict__ offs, const int* __restrict__ bsum,
                             int* __restrict__ cursor) {
    int i = blockIdx.x * 256 + threadIdx.x;
    if (i < NN) {
        int o = offs[i] + bsum[blockIdx.x];
        offs[i] = o;
        cursor[i] = o;
    }
    if (i == 0) offs[NN] = EE;
}

// ---------------- bucket edges into CSR (only 800K 4B atomics) ------------
__global__ void bucket_kernel(const int* __restrict__ src, const int* __restrict__ dst,
                              int* __restrict__ cursor, int* __restrict__ esrc) {
    int e = blockIdx.x * 256 + threadIdx.x;
    if (e < EE) {
        int d = dst[e];
        int pos = atomicAdd(&cursor[d], 1);
        esrc[pos] = src[e];
    }
}

// ---------------- gather-aggregate: agg[n] = mean over neighbors ----------
// 16 lanes per node (float4 each) -> 256B coalesced row reads; 16 nodes/block.
__global__ void gather_kernel(const float* __restrict__ feat,
                              const int* __restrict__ esrc,
                              const int* __restrict__ offs,
                              const float* __restrict__ inv,
                              float* __restrict__ agg) {
    int n = blockIdx.x * 16 + (threadIdx.x >> 4);
    if (n >= NN) return;
    int q = (threadIdx.x & 15) << 2;
    int e0 = offs[n], e1 = offs[n + 1];
    float ax = 0.f, ay = 0.f, az = 0.f, aw = 0.f;
    int e = e0;
    for (; e + 1 < e1; e += 2) {
        int s0 = esrc[e], s1 = esrc[e + 1];
        float4 v0 = *reinterpret_cast<const float4*>(feat + (size_t)s0 * DD + q);
        float4 v1 = *reinterpret_cast<const float4*>(feat + (size_t)s1 * DD + q);
        ax += v0.x + v1.x; ay += v0.y + v1.y;
        az += v0.z + v1.z; aw += v0.w + v1.w;
    }
    if (e < e1) {
        int s0 = esrc[e];
        float4 v0 = *reinterpret_cast<const float4*>(feat + (size_t)s0 * DD + q);
        ax += v0.x; ay += v0.y; az += v0.z; aw += v0.w;
    }
    float iv = inv[n];
    float4 r = make_float4(ax * iv, ay * iv, az * iv, aw * iv);
    *reinterpret_cast<float4*>(agg + (size_t)n * DD + q) = r;
}

// ---------------- fused SAGE layer: out = [agg | xin] @ [Wl;Wr] + b --------
// agg is already the mean. 64 nodes x 64 cols per block; A in LDS with XOR
// swizzle; each thread computes a 4x4 register tile.
__launch_bounds__(256)
__global__ void layer_kernel(const float* __restrict__ agg,
                             const float* __restrict__ xin,
                             const float* __restrict__ Wl,
                             const float* __restrict__ Wr,
                             const float* __restrict__ bias,
                             float* __restrict__ outp,
                             int relu) {
    __shared__ float A[64 * 128];   // [node][k^sw], sw = (node&7)<<2
    __shared__ float W[128 * 64];   // [k][j]
    const int tid = threadIdx.x;
    const int base = blockIdx.x * 64;

    #pragma unroll
    for (int i = 0; i < 8; ++i) {
        int idx = (i * 256 + tid) * 4;       // 0..8191
        int k = idx >> 6, j = idx & 63;
        const float* sp = (k < 64) ? (Wl + k * 64 + j) : (Wr + (k - 64) * 64 + j);
        *reinterpret_cast<float4*>(&W[idx]) = *reinterpret_cast<const float4*>(sp);
    }

    #pragma unroll
    for (int i = 0; i < 8; ++i) {
        int t2 = i * 256 + tid;              // 0..2047
        int n  = t2 >> 5;                    // node in tile 0..63
        int c4 = (t2 & 31) * 4;              // k chunk 0,4,...,124
        int node = base + n;
        float4 v = make_float4(0.f, 0.f, 0.f, 0.f);
        if (node < NN) {
            if (c4 < 64)
                v = *reinterpret_cast<const float4*>(agg + (size_t)node * DD + c4);
            else
                v = *reinterpret_cast<const float4*>(xin + (size_t)node * DD + (c4 - 64));
        }
        int sw = (n & 7) << 2;
        *reinterpret_cast<float4*>(&A[n * 128 + (c4 ^ sw)]) = v;
    }
    __syncthreads();

    const int tc = (tid & 15) * 4;
    const int tr = (tid >> 4) * 4;

    float acc[4][4];
    float4 bv = *reinterpret_cast<const float4*>(bias + tc);
    #pragma unroll
    for (int i = 0; i < 4; ++i) {
        acc[i][0] = bv.x; acc[i][1] = bv.y; acc[i][2] = bv.z; acc[i][3] = bv.w;
    }

    #pragma unroll 8
    for (int k = 0; k < 128; k += 4) {
        float av[4][4];
        #pragma unroll
        for (int i = 0; i < 4; ++i) {
            int row = tr + i;
            float4 a = *reinterpret_cast<const float4*>(
                &A[row * 128 + (k ^ ((row & 7) << 2))]);
            av[i][0] = a.x; av[i][1] = a.y; av[i][2] = a.z; av[i][3] = a.w;
        }
        #pragma unroll
        for (int kk = 0; kk < 4; ++kk) {
            float4 w = *reinterpret_cast<const float4*>(&W[(k + kk) * 64 + tc]);
            #pragma unroll
            for (int i = 0; i < 4; ++i) {
                acc[i][0] += av[i][kk] * w.x;
                acc[i][1] += av[i][kk] * w.y;
                acc[i][2] += av[i][kk] * w.z;
                acc[i][3] += av[i][kk] * w.w;
            }
        }
    }

    #pragma unroll
    for (int i = 0; i < 4; ++i) {
        int node = base + tr + i;
        if (node < NN) {
            float4 r = make_float4(acc[i][0], acc[i][1], acc[i][2], acc[i][3]);
            if (relu) {
                r.x = fmaxf(r.x, 0.f); r.y = fmaxf(r.y, 0.f);
                r.z = fmaxf(r.z, 0.f); r.w = fmaxf(r.w, 0.f);
            }
            *reinterpret_cast<float4*>(outp + (size_t)node * DD + tc) = r;
        }
    }
}

static inline size_t rup(size_t b) { return (b + 255) & ~(size_t)255; }

extern "C" void kernel_launch(void* const* d_in, const int* in_sizes, int n_in,
                              void* d_out, int out_size, void* d_ws, size_t ws_size,
                              hipStream_t stream) {
    const float* x   = (const float*)d_in[0];
    const int*   ei  = (const int*)d_in[1];
    const float* Wl1 = (const float*)d_in[2];
    const float* Wr1 = (const float*)d_in[3];
    const float* b1  = (const float*)d_in[4];
    const float* Wl2 = (const float*)d_in[5];
    const float* Wr2 = (const float*)d_in[6];
    const float* b2  = (const float*)d_in[7];
    float* out = (float*)d_out;

    const int* src = ei;        // edge_index[0]
    const int* dst = ei + EE;   // edge_index[1]

    // workspace layout (256B-aligned regions)
    char* p = (char*)d_ws;
    int* deg    = (int*)p;   p += rup((size_t)NN * 4);
    int* offs   = (int*)p;   p += rup((size_t)(NN + 1) * 4);
    int* cursor = (int*)p;   p += rup((size_t)NN * 4);
    int* bsum   = (int*)p;   p += rup(256 * 4);
    int* esrc   = (int*)p;   p += rup((size_t)EE * 4);
    float* inv  = (float*)p; p += rup((size_t)NN * 4);
    float* agg  = (float*)p; p += rup((size_t)NN * DD * 4);
    float* h    = out;       // layer-1 output lives in d_out (tiles partition nodes)

    const int NB = (NN + 255) / 256;     // 196

    hipMemsetAsync(deg, 0, (size_t)NN * sizeof(int), stream);

    // CSR build
    deg_kernel<<<(EE + 255) / 256, 256, 0, stream>>>(dst, deg);
    inv_kernel<<<NB, 256, 0, stream>>>(deg, inv);
    scan1_kernel<<<NB, 256, 0, stream>>>(deg, offs, bsum);
    scan2_kernel<<<1, 256, 0, stream>>>(bsum, NB);
    scan3_kernel<<<NB, 256, 0, stream>>>(offs, bsum, cursor);
    bucket_kernel<<<(EE + 255) / 256, 256, 0, stream>>>(src, dst, cursor, esrc);

    // layer 1
    gather_kernel<<<(NN + 15) / 16, 256, 0, stream>>>(x, esrc, offs, inv, agg);
    layer_kernel<<<(NN + 63) / 64, 256, 0, stream>>>(agg, x, Wl1, Wr1, b1, h, 1);

    // layer 2
    gather_kernel<<<(NN + 15) / 16, 256, 0, stream>>>(h, esrc, offs, inv, agg);
    layer_kernel<<<(NN + 63) / 64, 256, 0, stream>>>(agg, h, Wl2, Wr2, b2, out, 0);
}

// Round 3
// 223.284 us; speedup vs baseline: 6.5455x; 1.0740x over previous
//
#include <hip/hip_runtime.h>
#include <hip/hip_bf16.h>

#define NN 50000
#define EE 800000
#define DD 64

// ---------------- degree histogram: 4 edges/thread (ILP over atomics) -----
__global__ void deg_kernel(const int* __restrict__ dst, int* __restrict__ deg) {
    int e = (blockIdx.x * 256 + threadIdx.x) * 4;
    if (e < EE) {   // EE % 4 == 0, so all 4 lanes valid
        int4 d = *reinterpret_cast<const int4*>(dst + e);
        atomicAdd(&deg[d.x], 1);
        atomicAdd(&deg[d.y], 1);
        atomicAdd(&deg[d.z], 1);
        atomicAdd(&deg[d.w], 1);
    }
}

// ---------------- scan1: block-local exclusive scan + inv_deg -------------
__global__ void scan1_kernel(const int* __restrict__ deg, int* __restrict__ offs,
                             int* __restrict__ bsum, float* __restrict__ inv) {
    __shared__ int s[256];
    const int tid = threadIdx.x;
    int i = blockIdx.x * 256 + tid;
    int v = (i < NN) ? deg[i] : 0;
    s[tid] = v;
    __syncthreads();
    #pragma unroll
    for (int o = 1; o < 256; o <<= 1) {
        int t = (tid >= o) ? s[tid - o] : 0;
        __syncthreads();
        s[tid] += t;
        __syncthreads();
    }
    if (i < NN) {
        offs[i] = s[tid] - v;                  // exclusive within block
        inv[i]  = (v > 0) ? (1.0f / (float)v) : 0.0f;
    }
    if (tid == 255) bsum[blockIdx.x] = s[255]; // block total
}

__global__ void scan2_kernel(int* __restrict__ bsum, int nb) {
    __shared__ int s[256];
    const int tid = threadIdx.x;
    int v = (tid < nb) ? bsum[tid] : 0;
    s[tid] = v;
    __syncthreads();
    #pragma unroll
    for (int o = 1; o < 256; o <<= 1) {
        int t = (tid >= o) ? s[tid - o] : 0;
        __syncthreads();
        s[tid] += t;
        __syncthreads();
    }
    if (tid < nb) bsum[tid] = s[tid] - v;      // exclusive
}

__global__ void scan3_kernel(int* __restrict__ offs, const int* __restrict__ bsum,
                             int* __restrict__ cursor) {
    int i = blockIdx.x * 256 + threadIdx.x;
    if (i < NN) {
        int o = offs[i] + bsum[blockIdx.x];
        offs[i] = o;
        cursor[i] = o;
    }
    if (i == 0) offs[NN] = EE;
}

// ---------------- bucket: 4 edges/thread, 4 independent atomic chains -----
__global__ void bucket_kernel(const int* __restrict__ src, const int* __restrict__ dst,
                              int* __restrict__ cursor, int* __restrict__ esrc) {
    int e = (blockIdx.x * 256 + threadIdx.x) * 4;
    if (e < EE) {   // EE % 4 == 0
        int4 d = *reinterpret_cast<const int4*>(dst + e);
        int4 s = *reinterpret_cast<const int4*>(src + e);
        int p0 = atomicAdd(&cursor[d.x], 1);
        int p1 = atomicAdd(&cursor[d.y], 1);
        int p2 = atomicAdd(&cursor[d.z], 1);
        int p3 = atomicAdd(&cursor[d.w], 1);
        esrc[p0] = s.x;
        esrc[p1] = s.y;
        esrc[p2] = s.z;
        esrc[p3] = s.w;
    }
}

// ---------------- gather-aggregate: agg[n] = mean over neighbors ----------
// 16 lanes per node (float4 each); 4-edge unroll for 4 loads in flight.
__global__ void gather_kernel(const float* __restrict__ feat,
                              const int* __restrict__ esrc,
                              const int* __restrict__ offs,
                              const float* __restrict__ inv,
                              float* __restrict__ agg) {
    int n = blockIdx.x * 16 + (threadIdx.x >> 4);
    if (n >= NN) return;
    int q = (threadIdx.x & 15) << 2;
    int e0 = offs[n], e1 = offs[n + 1];
    float ax = 0.f, ay = 0.f, az = 0.f, aw = 0.f;
    int e = e0;
    for (; e + 3 < e1; e += 4) {
        int s0 = esrc[e], s1 = esrc[e + 1], s2 = esrc[e + 2], s3 = esrc[e + 3];
        float4 v0 = *reinterpret_cast<const float4*>(feat + (size_t)s0 * DD + q);
        float4 v1 = *reinterpret_cast<const float4*>(feat + (size_t)s1 * DD + q);
        float4 v2 = *reinterpret_cast<const float4*>(feat + (size_t)s2 * DD + q);
        float4 v3 = *reinterpret_cast<const float4*>(feat + (size_t)s3 * DD + q);
        ax += (v0.x + v1.x) + (v2.x + v3.x);
        ay += (v0.y + v1.y) + (v2.y + v3.y);
        az += (v0.z + v1.z) + (v2.z + v3.z);
        aw += (v0.w + v1.w) + (v2.w + v3.w);
    }
    for (; e < e1; ++e) {
        int s0 = esrc[e];
        float4 v0 = *reinterpret_cast<const float4*>(feat + (size_t)s0 * DD + q);
        ax += v0.x; ay += v0.y; az += v0.z; aw += v0.w;
    }
    float iv = inv[n];
    float4 r = make_float4(ax * iv, ay * iv, az * iv, aw * iv);
    *reinterpret_cast<float4*>(agg + (size_t)n * DD + q) = r;
}

// ---------------- fused SAGE layer: out = [agg | xin] @ [Wl;Wr] + b --------
__launch_bounds__(256)
__global__ void layer_kernel(const float* __restrict__ agg,
                             const float* __restrict__ xin,
                             const float* __restrict__ Wl,
                             const float* __restrict__ Wr,
                             const float* __restrict__ bias,
                             float* __restrict__ outp,
                             int relu) {
    __shared__ float A[64 * 128];   // [node][k^sw], sw = (node&7)<<2
    __shared__ float W[128 * 64];   // [k][j]
    const int tid = threadIdx.x;
    const int base = blockIdx.x * 64;

    #pragma unroll
    for (int i = 0; i < 8; ++i) {
        int idx = (i * 256 + tid) * 4;       // 0..8191
        int k = idx >> 6, j = idx & 63;
        const float* sp = (k < 64) ? (Wl + k * 64 + j) : (Wr + (k - 64) * 64 + j);
        *reinterpret_cast<float4*>(&W[idx]) = *reinterpret_cast<const float4*>(sp);
    }

    #pragma unroll
    for (int i = 0; i < 8; ++i) {
        int t2 = i * 256 + tid;              // 0..2047
        int n  = t2 >> 5;                    // node in tile 0..63
        int c4 = (t2 & 31) * 4;              // k chunk 0,4,...,124
        int node = base + n;
        float4 v = make_float4(0.f, 0.f, 0.f, 0.f);
        if (node < NN) {
            if (c4 < 64)
                v = *reinterpret_cast<const float4*>(agg + (size_t)node * DD + c4);
            else
                v = *reinterpret_cast<const float4*>(xin + (size_t)node * DD + (c4 - 64));
        }
        int sw = (n & 7) << 2;
        *reinterpret_cast<float4*>(&A[n * 128 + (c4 ^ sw)]) = v;
    }
    __syncthreads();

    const int tc = (tid & 15) * 4;
    const int tr = (tid >> 4) * 4;

    float acc[4][4];
    float4 bv = *reinterpret_cast<const float4*>(bias + tc);
    #pragma unroll
    for (int i = 0; i < 4; ++i) {
        acc[i][0] = bv.x; acc[i][1] = bv.y; acc[i][2] = bv.z; acc[i][3] = bv.w;
    }

    #pragma unroll 8
    for (int k = 0; k < 128; k += 4) {
        float av[4][4];
        #pragma unroll
        for (int i = 0; i < 4; ++i) {
            int row = tr + i;
            float4 a = *reinterpret_cast<const float4*>(
                &A[row * 128 + (k ^ ((row & 7) << 2))]);
            av[i][0] = a.x; av[i][1] = a.y; av[i][2] = a.z; av[i][3] = a.w;
        }
        #pragma unroll
        for (int kk = 0; kk < 4; ++kk) {
            float4 w = *reinterpret_cast<const float4*>(&W[(k + kk) * 64 + tc]);
            #pragma unroll
            for (int i = 0; i < 4; ++i) {
                acc[i][0] += av[i][kk] * w.x;
                acc[i][1] += av[i][kk] * w.y;
                acc[i][2] += av[i][kk] * w.z;
                acc[i][3] += av[i][kk] * w.w;
            }
        }
    }

    #pragma unroll
    for (int i = 0; i < 4; ++i) {
        int node = base + tr + i;
        if (node < NN) {
            float4 r = make_float4(acc[i][0], acc[i][1], acc[i][2], acc[i][3]);
            if (relu) {
                r.x = fmaxf(r.x, 0.f); r.y = fmaxf(r.y, 0.f);
                r.z = fmaxf(r.z, 0.f); r.w = fmaxf(r.w, 0.f);
            }
            *reinterpret_cast<float4*>(outp + (size_t)node * DD + tc) = r;
        }
    }
}

static inline size_t rup(size_t b) { return (b + 255) & ~(size_t)255; }

extern "C" void kernel_launch(void* const* d_in, const int* in_sizes, int n_in,
                              void* d_out, int out_size, void* d_ws, size_t ws_size,
                              hipStream_t stream) {
    const float* x   = (const float*)d_in[0];
    const int*   ei  = (const int*)d_in[1];
    const float* Wl1 = (const float*)d_in[2];
    const float* Wr1 = (const float*)d_in[3];
    const float* b1  = (const float*)d_in[4];
    const float* Wl2 = (const float*)d_in[5];
    const float* Wr2 = (const float*)d_in[6];
    const float* b2  = (const float*)d_in[7];
    float* out = (float*)d_out;

    const int* src = ei;        // edge_index[0]
    const int* dst = ei + EE;   // edge_index[1]

    // workspace layout (256B-aligned regions)
    char* p = (char*)d_ws;
    int* deg    = (int*)p;   p += rup((size_t)NN * 4);
    int* offs   = (int*)p;   p += rup((size_t)(NN + 1) * 4);
    int* cursor = (int*)p;   p += rup((size_t)NN * 4);
    int* bsum   = (int*)p;   p += rup(256 * 4);
    int* esrc   = (int*)p;   p += rup((size_t)EE * 4);
    float* inv  = (float*)p; p += rup((size_t)NN * 4);
    float* agg  = (float*)p; p += rup((size_t)NN * DD * 4);
    float* h    = out;       // layer-1 output lives in d_out (tiles partition nodes)

    const int NB = (NN + 255) / 256;     // 196

    hipMemsetAsync(deg, 0, (size_t)NN * sizeof(int), stream);

    // CSR build
    deg_kernel<<<(EE / 4 + 255) / 256, 256, 0, stream>>>(dst, deg);
    scan1_kernel<<<NB, 256, 0, stream>>>(deg, offs, bsum, inv);
    scan2_kernel<<<1, 256, 0, stream>>>(bsum, NB);
    scan3_kernel<<<NB, 256, 0, stream>>>(offs, bsum, cursor);
    bucket_kernel<<<(EE / 4 + 255) / 256, 256, 0, stream>>>(src, dst, cursor, esrc);

    // layer 1
    gather_kernel<<<(NN + 15) / 16, 256, 0, stream>>>(x, esrc, offs, inv, agg);
    layer_kernel<<<(NN + 63) / 64, 256, 0, stream>>>(agg, x, Wl1, Wr1, b1, h, 1);

    // layer 2
    gather_kernel<<<(NN + 15) / 16, 256, 0, stream>>>(h, esrc, offs, inv, agg);
    layer_kernel<<<(NN + 63) / 64, 256, 0, stream>>>(agg, h, Wl2, Wr2, b2, out, 0);
}